// Round 3
// baseline (212.993 us; speedup 1.0000x reference)
//
#include <hip/hip_runtime.h>

// BlockRelLinear round 7: occupancy experiment. 64KB LDS pair-slice -> 2 blocks/CU,
// 32 waves/CU (was 128KB quad -> 1 block/CU, 16 waves).
// out[p, n*8+o] = sum_i x[p, n*8+i] * w[rel[p], n, i, o]
//
// Round-6 post-mortem: swizzle fix verified (conflicts 1.35e7 -> 4.26e6) but
// dur unchanged 73.9us. r4 (sorted/register-weights), r5, r6 ALL sit at 72-74us
// with HBM 26%, VALU 10%, LDS ~32% busy -> nothing saturated = latency-bound.
// Common cap across all three: waves/CU. This round isolates wave count 16->32:
//  - 8 pairs (n = q*2+nl), per-block weight slice 128r x 2n x 16chunks x 16B = 64KB.
//  - grid 512 = 8 pairs x 64 blocks; q = bid>>6 so paired blocks (same b) land on
//    the same XCD (64 % 8 == 0) and share x/out 128B lines in one L2.
//  - swizzle pos = ((k<<1)|nl) ^ (r&31): bank-quad bits get nl(bit0), half(bit1),
//    i(bit2) XOR r -> same-point lanes in distinct quads, r rotates points. Same
//    conflict math as r6 (~1.4x floor).
//  - depth-2 prefetch kept; FMA i-order unchanged -> absmax 0.0.
// Device-wide LDS instrs and HBM bytes identical to r6 -> clean A/B on wave count.

__global__ __launch_bounds__(1024, 8) void k_fused(
    const float* __restrict__ x, const float* __restrict__ w,
    const int* __restrict__ rel, float* __restrict__ out, int npoints)
{
    // wlds[r][pos], pos = ((k<<1)|nl) ^ (r&31); k = i*2 + half (16 chunks), nl = n&1
    __shared__ float4 wlds[128][32];             // 64 KB

    const int q = blockIdx.x >> 6;               // pair 0..7 (n = q*2 + nl)
    const int b = blockIdx.x & 63;               // 64 blocks per pair

    // ---- stage pair weights, swizzled (full permuted rows -> conflict-free) ----
    const float4* wsrc = reinterpret_cast<const float4*>(w);
    #pragma unroll
    for (int j = 0; j < 4; ++j) {
        int f   = threadIdx.x + j * 1024;        // 0..4095 = (r, nl, k)
        int r   = f >> 5;
        int lo  = f & 31;                        // nl*16 + k
        int nls = lo >> 4;
        int k   = f & 15;
        wlds[r][((k << 1) | nls) ^ (r & 31)] = wsrc[r * 256 + (q * 2 + nls) * 16 + k];
    }
    __syncthreads();

    const int nl = threadIdx.x & 1;
    const int pt = threadIdx.x >> 1;             // 0..511
    const int chunk = (npoints + 63) >> 6;       // 64 blocks per pair
    const int plo = b * chunk;
    const int phi = min(plo + chunk, npoints);
    const int n  = q * 2 + nl;

    int p1 = plo + pt;
    if (p1 >= phi) return;                       // no further __syncthreads

    const float* xb = x + n * 8;
    float*       ob = out + n * 8;

    // ---- pipeline prologue: slots 1 and 2 in flight ----
    int r1 = rel[p1];
    const float4* xv1 = reinterpret_cast<const float4*>(xb + (size_t)p1 * 128);
    float4 xa1 = xv1[0], xb1 = xv1[1];

    int p2 = p1 + 512;
    int p2c = p2 < phi ? p2 : phi - 1;
    int r2 = rel[p2c];
    const float4* xv2 = reinterpret_cast<const float4*>(xb + (size_t)p2c * 128);
    float4 xa2 = xv2[0], xb2 = xv2[1];

    while (true) {
        // ---- depth-2 prefetch ----
        int p3 = p1 + 1024;
        int p3c = p3 < phi ? p3 : phi - 1;
        int r3 = rel[p3c];
        const float4* xv3 = reinterpret_cast<const float4*>(xb + (size_t)p3c * 128);
        float4 xa3 = xv3[0], xb3 = xv3[1];

        // ---- compute current point p1 ----
        {
            const int s   = r1 & 31;
            const int sHi = s & 0x1C;            // bits 2..4
            const int low = nl ^ (s & 3);        // bits 0..1
            const float4* base = wlds[r1];
            const float4* wrA = base + low;        // half 0 chunks (c even)
            const float4* wrB = base + (low ^ 2);  // half 1 chunks (c odd)
            float xf[8] = {xa1.x, xa1.y, xa1.z, xa1.w,
                           xb1.x, xb1.y, xb1.z, xb1.w};
            float a0 = 0.f, a1 = 0.f, a2 = 0.f, a3 = 0.f;
            float a4 = 0.f, a5 = 0.f, a6 = 0.f, a7 = 0.f;
            #pragma unroll
            for (int i = 0; i < 8; ++i) {        // ascending i: same FMA order as r2-r6
                int off = (i << 2) ^ sHi;        // disjoint bit fields vs low/2
                float4 wA = wrA[off];            // w[r][n][i][0..4)
                float4 wB = wrB[off];            // w[r][n][i][4..8)
                float xi = xf[i];
                a0 = fmaf(xi, wA.x, a0);
                a1 = fmaf(xi, wA.y, a1);
                a2 = fmaf(xi, wA.z, a2);
                a3 = fmaf(xi, wA.w, a3);
                a4 = fmaf(xi, wB.x, a4);
                a5 = fmaf(xi, wB.y, a5);
                a6 = fmaf(xi, wB.z, a6);
                a7 = fmaf(xi, wB.w, a7);
            }
            float4* ov = reinterpret_cast<float4*>(ob + (size_t)p1 * 128);
            ov[0] = make_float4(a0, a1, a2, a3);
            ov[1] = make_float4(a4, a5, a6, a7);
        }

        if (p2 >= phi) break;
        p1 = p2;  r1 = r2; xa1 = xa2; xb1 = xb2;
        p2 = p3;  r2 = r3; xa2 = xa3; xb2 = xb3;
    }
}

// ---------- fallback (round-2 kernel) for unexpected shapes ----------
__global__ __launch_bounds__(256) void brl_kernel(
    const float* __restrict__ x, const float* __restrict__ w,
    const int* __restrict__ rel, float* __restrict__ out, int npoints)
{
    int tid = blockIdx.x * 256 + threadIdx.x;
    int p = tid >> 4;
    if (p >= npoints) return;
    int n = tid & 15;
    int r = rel[p];
    const float4* xv = reinterpret_cast<const float4*>(x + (size_t)p * 128 + n * 8);
    float4 x0 = xv[0], x1 = xv[1];
    float xf[8] = {x0.x, x0.y, x0.z, x0.w, x1.x, x1.y, x1.z, x1.w};
    const float4* wv = reinterpret_cast<const float4*>(w + ((size_t)r * 16 + n) * 64);
    float acc[8] = {0.f, 0.f, 0.f, 0.f, 0.f, 0.f, 0.f, 0.f};
    #pragma unroll
    for (int i = 0; i < 8; ++i) {
        float4 w0 = wv[2 * i], w1 = wv[2 * i + 1];
        float wf[8] = {w0.x, w0.y, w0.z, w0.w, w1.x, w1.y, w1.z, w1.w};
        #pragma unroll
        for (int o = 0; o < 8; ++o) acc[o] = fmaf(xf[i], wf[o], acc[o]);
    }
    float4* ov = reinterpret_cast<float4*>(out + (size_t)p * 128 + n * 8);
    ov[0] = make_float4(acc[0], acc[1], acc[2], acc[3]);
    ov[1] = make_float4(acc[4], acc[5], acc[6], acc[7]);
}

extern "C" void kernel_launch(void* const* d_in, const int* in_sizes, int n_in,
                              void* d_out, int out_size, void* d_ws, size_t ws_size,
                              hipStream_t stream) {
    const float* x   = (const float*)d_in[0];
    const float* w   = (const float*)d_in[1];
    const int*   rel = (const int*)d_in[2];
    float*       out = (float*)d_out;

    int npoints = in_sizes[2];
    int R = in_sizes[1] / 1024;          // R * nb(16) * ib(8) * ob(8)

    if (R == 128 && in_sizes[0] == npoints * 128) {
        k_fused<<<512, 1024, 0, stream>>>(x, w, rel, out, npoints);
    } else {
        int total = npoints * 16;
        brl_kernel<<<(total + 255) / 256, 256, 0, stream>>>(x, w, rel, out, npoints);
    }
}

// Round 4
// 190.482 us; speedup vs baseline: 1.1182x; 1.1182x over previous
//
#include <hip/hip_runtime.h>

// BlockRelLinear round 8: lane-dense vmem remap.
// out[p, n*8+o] = sum_i x[p, n*8+i] * w[rel[p], n, i, o]
//
// Evidence r4-r7: four structures all ~72-78us, ~2.1 TB/s, no pipe >35%,
// occupancy-insensitive (r7: 16->32 waves, +5% SLOWER), conflict-insensitive
// (r6: 3x fewer, no change), LDS-insensitive (r4: none, same). Shared trait:
// sparse line coverage per vmem instr (r6: 16 lines @ 50% per dwordx4; r7: 32
// lines @ 50%, and r7 was slower in proportion). Theory: CU vmem front end is
// line-touch limited, not byte limited. m13's 6.3TB/s copy is lane-dense.
//
// This round: identical to r6 EXCEPT lane map. lane = pt8*8 + j; j = 16B chunk
// of the point's 128B quad-column (j = nl*2+h, nl = n within quad, h = o-half).
// Each lane loads/stores exactly its 16B chunk -> every wave-instr covers 8
// FULLY-covered consecutive-16B-lane lines (1 touch/line, was 2). The 32B x
// slice a lane consumes is completed from its pair-lane via DPP quad_perm
// (VALU pipe, no LDS). Each lane computes 4 outputs (h-half). FMA i-order
// ascending, unchanged -> absmax 0.0. LDS layout/swizzle identical to r6.

__device__ __forceinline__ float4 dpp_swap1(float4 v) {
    union { float4 f; int i[4]; } a, b;
    a.f = v;
    // quad_perm [1,0,3,2] = 0xB1 : lane <- lane^1
    b.i[0] = __builtin_amdgcn_update_dpp(0, a.i[0], 0xB1, 0xF, 0xF, true);
    b.i[1] = __builtin_amdgcn_update_dpp(0, a.i[1], 0xB1, 0xF, 0xF, true);
    b.i[2] = __builtin_amdgcn_update_dpp(0, a.i[2], 0xB1, 0xF, 0xF, true);
    b.i[3] = __builtin_amdgcn_update_dpp(0, a.i[3], 0xB1, 0xF, 0xF, true);
    return b.f;
}

__global__ __launch_bounds__(1024) void k_fused(
    const float* __restrict__ x, const float* __restrict__ w,
    const int* __restrict__ rel, float* __restrict__ out, int npoints)
{
    // wlds[r][pos], pos = ((c<<2)|nl) ^ (r&63); c = i*2 + h (16 chunks), nl = n&3
    __shared__ float4 wlds[128][64];             // 128 KB (1 block/CU)

    const int q = blockIdx.x >> 6;               // quad 0..3 (n = q*4 + nl)
    const int b = blockIdx.x & 63;               // same-b quad blocks: same XCD (64%8==0)

    // ---- stage quad weights, swizzled (identical to r6) ----
    const float4* wsrc = reinterpret_cast<const float4*>(w);
    #pragma unroll
    for (int j = 0; j < 8; ++j) {
        int f  = threadIdx.x + j * 1024;         // (r, nl, k)
        int r  = f >> 6;
        int lo = f & 63;                         // nl*16 + k
        int nl = lo >> 4;
        int k  = f & 15;
        wlds[r][((k << 2) | nl) ^ (r & 63)] = wsrc[r * 256 + q * 64 + lo];
    }
    __syncthreads();

    const int lane = threadIdx.x & 63;
    const int wv   = threadIdx.x >> 6;           // wave 0..15
    const int pt8  = lane >> 3;                  // 8 points per wave-group
    const int j    = lane & 7;                   // 16B chunk within 128B column
    const int nl   = j >> 1;
    const int h    = j & 1;                      // output half (o = h*4..h*4+3)

    const int chunk = (npoints + 63) >> 6;
    const int plo = b * chunk;
    const int phi = min(plo + chunk, npoints);

    int g1 = plo + wv * 8;                       // wave-uniform group base
    if (g1 >= phi) return;                       // no further __syncthreads

    // float4 index for point p: p*32 + q*8 + j  (lane-dense: 8 full lines/instr)
    const float4* xv = reinterpret_cast<const float4*>(x) + q * 8 + j;
    float4*       ov = reinterpret_cast<float4*>(out) + q * 8 + j;

    // ---- pipeline prologue: slots 1 and 2 in flight (depth-2, as r6) ----
    int p1  = g1 + pt8;
    int p1c = min(p1, phi - 1);
    int r1  = rel[p1c];
    float4 xa1 = xv[(size_t)p1c * 32];

    int g2  = g1 + 128;                          // 16 waves * 8 points
    int p2c = min(g2 + pt8, phi - 1);
    int r2  = rel[p2c];
    float4 xa2 = xv[(size_t)p2c * 32];

    while (true) {
        // ---- depth-2 prefetch ----
        int g3  = g1 + 256;
        int p3c = min(g3 + pt8, phi - 1);
        int r3  = rel[p3c];
        float4 xa3 = xv[(size_t)p3c * 32];

        // ---- compute group g1 ----
        {
            float4 xo  = dpp_swap1(xa1);         // pair-lane's chunk
            float4 xlo = h ? xo  : xa1;          // x[p, n*8 .. +4)
            float4 xhi = h ? xa1 : xo;           // x[p, n*8+4 .. +8)
            const int s   = r1 & 63;
            const int thi = s & 0x38;            // XORs i-bits
            const int t0  = ((h << 2) | nl) ^ (s & 7);
            const float4* base = wlds[r1];
            float xf[8] = {xlo.x, xlo.y, xlo.z, xlo.w,
                           xhi.x, xhi.y, xhi.z, xhi.w};
            float a0 = 0.f, a1 = 0.f, a2 = 0.f, a3 = 0.f;
            #pragma unroll
            for (int i = 0; i < 8; ++i) {        // ascending i: FMA order as r2-r7
                float4 wv4 = base[((i << 3) ^ thi) | t0];  // w[r][n][i][h*4..+4)
                float xi = xf[i];
                a0 = fmaf(xi, wv4.x, a0);
                a1 = fmaf(xi, wv4.y, a1);
                a2 = fmaf(xi, wv4.z, a2);
                a3 = fmaf(xi, wv4.w, a3);
            }
            if (p1 < phi)
                ov[(size_t)p1 * 32] = make_float4(a0, a1, a2, a3);
        }

        if (g2 >= phi) break;
        g1 = g2; p1 = g1 + pt8; r1 = r2; xa1 = xa2;
        g2 = g3;                r2 = r3; xa2 = xa3;
    }
}

// ---------- fallback (round-2 kernel) for unexpected shapes ----------
__global__ __launch_bounds__(256) void brl_kernel(
    const float* __restrict__ x, const float* __restrict__ w,
    const int* __restrict__ rel, float* __restrict__ out, int npoints)
{
    int tid = blockIdx.x * 256 + threadIdx.x;
    int p = tid >> 4;
    if (p >= npoints) return;
    int n = tid & 15;
    int r = rel[p];
    const float4* xv = reinterpret_cast<const float4*>(x + (size_t)p * 128 + n * 8);
    float4 x0 = xv[0], x1 = xv[1];
    float xf[8] = {x0.x, x0.y, x0.z, x0.w, x1.x, x1.y, x1.z, x1.w};
    const float4* wv = reinterpret_cast<const float4*>(w + ((size_t)r * 16 + n) * 64);
    float acc[8] = {0.f, 0.f, 0.f, 0.f, 0.f, 0.f, 0.f, 0.f};
    #pragma unroll
    for (int i = 0; i < 8; ++i) {
        float4 w0 = wv[2 * i], w1 = wv[2 * i + 1];
        float wf[8] = {w0.x, w0.y, w0.z, w0.w, w1.x, w1.y, w1.z, w1.w};
        #pragma unroll
        for (int o = 0; o < 8; ++o) acc[o] = fmaf(xf[i], wf[o], acc[o]);
    }
    float4* ov = reinterpret_cast<float4*>(out + (size_t)p * 128 + n * 8);
    ov[0] = make_float4(acc[0], acc[1], acc[2], acc[3]);
    ov[1] = make_float4(acc[4], acc[5], acc[6], acc[7]);
}

extern "C" void kernel_launch(void* const* d_in, const int* in_sizes, int n_in,
                              void* d_out, int out_size, void* d_ws, size_t ws_size,
                              hipStream_t stream) {
    const float* x   = (const float*)d_in[0];
    const float* w   = (const float*)d_in[1];
    const int*   rel = (const int*)d_in[2];
    float*       out = (float*)d_out;

    int npoints = in_sizes[2];
    int R = in_sizes[1] / 1024;          // R * nb(16) * ib(8) * ob(8)

    if (R == 128 && in_sizes[0] == npoints * 128) {
        k_fused<<<256, 1024, 0, stream>>>(x, w, rel, out, npoints);
    } else {
        int total = npoints * 16;
        brl_kernel<<<(total + 255) / 256, 256, 0, stream>>>(x, w, rel, out, npoints);
    }
}